// Round 4
// baseline (314.909 us; speedup 1.0000x reference)
//
#include <hip/hip_runtime.h>
#include <math.h>

// Attention pooling: context[b,d] = sum_t softmax_t( V . tanh(full[b,t,:]@W1 + last[b,:]@W2 + b1+b2) ) * full[b,t,d]
// B=32 T=2048 D=512 U=512, fp32 in/out. bV softmax-invariant -> dropped; b1+b2 folded into h2.
// R4: score kernel barrier-light: B fragments load global->register (W1T hot in L2; no LDS, no
//     cross-wave dependency); only A staged in LDS (K-quarter, XOR-swizzled chunks). Context kernel
//     rebuilt tile-owned (<=2 atomics/element instead of 32-way contention).
// ws (floats): scores [B*T] @0, h2 [B*U] @B*T, then W1T [U*D] bf16 (shorts).

#define BB 32
#define TT 2048
#define DD 512
#define UU 512

typedef short bf16x8 __attribute__((ext_vector_type(8)));
typedef float f32x4  __attribute__((ext_vector_type(4)));

static __device__ __forceinline__ short f2bf(float f) {
    unsigned x = __float_as_uint(f);
    return (short)((x + 0x7fffu + ((x >> 16) & 1u)) >> 16);   // RNE
}

static __device__ __forceinline__ float fast_tanh(float x) {
    float e = __expf(2.f * x);
    return 1.f - 2.f * __builtin_amdgcn_rcpf(e + 1.f);
}

// ---------------- prep: blocks [0,256): W1T[u][d]=bf16(W1[d][u]); [256,288): h2 ----------------
__global__ __launch_bounds__(256) void prep_kernel(const float* __restrict__ W1,
                                                   short* __restrict__ W1T,
                                                   const float* __restrict__ last,
                                                   const float* __restrict__ W2,
                                                   const float* __restrict__ b1,
                                                   const float* __restrict__ b2,
                                                   float* __restrict__ h2) {
    __shared__ float tile[32][33];
    __shared__ float ls[DD];
    const int bid = blockIdx.x;
    const int tid = threadIdx.x;
    if (bid < 256) {
        const int tr = (bid >> 4) << 5;   // d-block origin
        const int tc = (bid & 15) << 5;   // u-block origin
#pragma unroll
        for (int p = 0; p < 4; ++p) {
            const int r = p * 8 + (tid >> 5), c = tid & 31;
            tile[r][c] = W1[(size_t)(tr + r) * UU + tc + c];
        }
        __syncthreads();
#pragma unroll
        for (int p = 0; p < 4; ++p) {
            const int r = p * 8 + (tid >> 5), c = tid & 31;    // r=u-local, c=d-local
            W1T[(size_t)(tc + r) * DD + tr + c] = f2bf(tile[c][r]);
        }
    } else {
        const int b = bid - 256;
        for (int i = tid; i < DD; i += 256) ls[i] = last[b * DD + i];
        __syncthreads();
        float a0 = 0.f, a1 = 0.f;
#pragma unroll 8
        for (int d = 0; d < DD; ++d) {
            const float l = ls[d];
            a0 += l * W2[d * UU + tid];
            a1 += l * W2[d * UU + tid + 256];
        }
        h2[b * UU + tid]       = a0 + b1[tid] + b2[tid];
        h2[b * UU + tid + 256] = a1 + b1[tid + 256] + b2[tid + 256];
    }
}

// ---------------- score: scores[b,t] = V . tanh(full[b,t,:]@W1 + h2[b,:]) — bf16 MFMA, M=64 ----------------
// 1024 blocks: b = bid>>5, t0 = (bid&31)*64. 4 waves; wave w owns u in [w*128,(w+1)*128).
// B frags: global->register from W1T (L2-hot). A: LDS K-quarter (64 x 128 bf16 = 16 KB),
// chunk(row,cc) at slot row*16 + (cc ^ (row&15)) -> 2-way conflicts only (free).
// Barriers: 2 per K-quarter (8 total) instead of 2 per K-step (32).
__global__ __launch_bounds__(256, 2) void score_kernel(const float* __restrict__ full,
                                                       const short* __restrict__ W1T,
                                                       const float* __restrict__ h2,
                                                       const float* __restrict__ V,
                                                       float* __restrict__ scores) {
    __shared__ __align__(16) short a_lds[1024 * 8];   // 1024 16B chunks = 16 KB
    __shared__ float score_red[4][64];

    const int bid = blockIdx.x;
    const int b  = bid >> 5;
    const int t0 = (bid & 31) << 6;
    const int tid = threadIdx.x;
    const int w    = tid >> 6;
    const int lane = tid & 63;
    const int quad = lane >> 4;
    const int col  = lane & 15;

    f32x4 acc[4][8];
#pragma unroll
    for (int i = 0; i < 4; ++i)
#pragma unroll
        for (int j = 0; j < 8; ++j) acc[i][j] = (f32x4){0.f, 0.f, 0.f, 0.f};

    const size_t fullbase = (size_t)(b * TT + t0) * DD;
    const short* bbase = W1T + (size_t)(w * 128 + col) * DD + quad * 8;

    for (int ko = 0; ko < 4; ++ko) {
        if (ko > 0) __syncthreads();              // protect a_lds reuse
        // stage A quarter: rows 0..63, k in [ko*128, (ko+1)*128), fp32 -> bf16
#pragma unroll
        for (int i = 0; i < 4; ++i) {
            const int id  = tid + 256 * i;        // chunk slot 0..1023
            const int row = id >> 4;
            const int cc  = (id & 15) ^ (row & 15);
            const float* src = &full[fullbase + (size_t)row * DD + ko * 128 + cc * 8];
            const float4 v0 = *(const float4*)src;
            const float4 v1 = *(const float4*)(src + 4);
            bf16x8 pk = {f2bf(v0.x), f2bf(v0.y), f2bf(v0.z), f2bf(v0.w),
                         f2bf(v1.x), f2bf(v1.y), f2bf(v1.z), f2bf(v1.w)};
            *(bf16x8*)&a_lds[id * 8] = pk;
        }
        __syncthreads();

        for (int ki = 0; ki < 4; ++ki) {
            bf16x8 af[4];
#pragma unroll
            for (int mt = 0; mt < 4; ++mt) {
                const int row = mt * 16 + col;
                const int sl  = row * 16 + ((ki * 4 + quad) ^ col);
                af[mt] = *(const bf16x8*)&a_lds[sl * 8];
            }
            const int kg = ko * 128 + ki * 32;    // + quad*8 folded into bbase
#pragma unroll
            for (int nt = 0; nt < 8; ++nt) {
                const bf16x8 bf = *(const bf16x8*)&bbase[(size_t)nt * 16 * DD + kg];
#pragma unroll
                for (int mt = 0; mt < 4; ++mt)
                    acc[mt][nt] = __builtin_amdgcn_mfma_f32_16x16x32_bf16(af[mt], bf, acc[mt][nt], 0, 0, 0);
            }
        }
    }

    // epilogue: tanh + dot with V over this wave's u-slice; rows = mt*16 + quad*4 + r
    float srow[16];
#pragma unroll
    for (int i = 0; i < 16; ++i) srow[i] = 0.f;
#pragma unroll
    for (int nt = 0; nt < 8; ++nt) {
        const int u = w * 128 + nt * 16 + col;
        const float hv = h2[b * UU + u];
        const float vv = V[u];
#pragma unroll
        for (int mt = 0; mt < 4; ++mt)
#pragma unroll
            for (int r = 0; r < 4; ++r)
                srow[mt * 4 + r] += fast_tanh(acc[mt][nt][r] + hv) * vv;
    }
#pragma unroll
    for (int off = 1; off < 16; off <<= 1) {
#pragma unroll
        for (int i = 0; i < 16; ++i) srow[i] += __shfl_xor(srow[i], off, 64);
    }
    if (col == 0) {
#pragma unroll
        for (int mt = 0; mt < 4; ++mt)
#pragma unroll
            for (int r = 0; r < 4; ++r)
                score_red[w][mt * 16 + quad * 4 + r] = srow[mt * 4 + r];
    }
    __syncthreads();
    if (tid < 64)
        scores[b * TT + t0 + tid] = score_red[0][tid] + score_red[1][tid] +
                                    score_red[2][tid] + score_red[3][tid];
}

// ---------------- softmax over T per batch; normalize in place; zero out ----------------
__global__ __launch_bounds__(256) void softmax_kernel(float* __restrict__ scores,
                                                      float* __restrict__ out) {
    const int b = blockIdx.x;
    const int tid = threadIdx.x;
    __shared__ float red[256];

    out[b * DD + tid] = 0.f;
    out[b * DD + 256 + tid] = 0.f;

    float local[8];
    float m = -1e30f;
#pragma unroll
    for (int i = 0; i < 8; ++i) {
        local[i] = scores[b * TT + i * 256 + tid];
        m = fmaxf(m, local[i]);
    }
    red[tid] = m;
    __syncthreads();
    for (int s = 128; s > 0; s >>= 1) {
        if (tid < s) red[tid] = fmaxf(red[tid], red[tid + s]);
        __syncthreads();
    }
    const float mx = red[0];
    __syncthreads();

    float sum = 0.f;
#pragma unroll
    for (int i = 0; i < 8; ++i) {
        local[i] = __expf(local[i] - mx);
        sum += local[i];
    }
    red[tid] = sum;
    __syncthreads();
    for (int s = 128; s > 0; s >>= 1) {
        if (tid < s) red[tid] += red[tid + s];
        __syncthreads();
    }
    const float inv = 1.f / red[0];
#pragma unroll
    for (int i = 0; i < 8; ++i) scores[b * TT + i * 256 + tid] = local[i] * inv;
}

// ---------------- context: block owns (b, 128-d-slice, T-half); <=2 atomics per out element ----------------
__global__ __launch_bounds__(256) void context_kernel(const float* __restrict__ full,
                                                      const float* __restrict__ p,
                                                      float* __restrict__ out) {
    const int bid = blockIdx.x;           // 256 blocks: b(5) | dslice(2) | thalf(1)
    const int b  = bid >> 3;
    const int d0 = ((bid >> 1) & 3) * 128;
    const int t0 = (bid & 1) * 1024;
    const int tid = threadIdx.x;
    const int c  = tid & 31;              // float4 column: d = d0 + c*4
    const int tr = tid >> 5;              // t residue mod 8

    __shared__ float ps[1024];
    __shared__ float4 red[256];
    for (int i = tid; i < 1024; i += 256) ps[i] = p[b * TT + t0 + i];
    __syncthreads();

    float ax = 0.f, ay = 0.f, az = 0.f, aw = 0.f;
    const float* base = full + ((size_t)(b * TT + t0)) * DD + d0;
#pragma unroll 4
    for (int it = 0; it < 128; ++it) {
        const int t = it * 8 + tr;
        const float4 v = *(const float4*)&base[(size_t)t * DD + c * 4];
        const float wg = ps[t];
        ax += wg * v.x; ay += wg * v.y; az += wg * v.z; aw += wg * v.w;
    }
    red[tid] = make_float4(ax, ay, az, aw);
    __syncthreads();
    if (tid < 32) {
        float4 s = red[tid];
#pragma unroll
        for (int g = 1; g < 8; ++g) {
            const float4 o = red[g * 32 + tid];
            s.x += o.x; s.y += o.y; s.z += o.z; s.w += o.w;
        }
        atomicAdd(&out[b * DD + d0 + tid * 4 + 0], s.x);
        atomicAdd(&out[b * DD + d0 + tid * 4 + 1], s.y);
        atomicAdd(&out[b * DD + d0 + tid * 4 + 2], s.z);
        atomicAdd(&out[b * DD + d0 + tid * 4 + 3], s.w);
    }
}

extern "C" void kernel_launch(void* const* d_in, const int* in_sizes, int n_in,
                              void* d_out, int out_size, void* d_ws, size_t ws_size,
                              hipStream_t stream) {
    const float* full = (const float*)d_in[0];
    const float* last = (const float*)d_in[1];
    const float* W1   = (const float*)d_in[2];
    const float* b1   = (const float*)d_in[3];
    const float* W2   = (const float*)d_in[4];
    const float* b2   = (const float*)d_in[5];
    const float* V    = (const float*)d_in[6];
    // d_in[7] = bV: softmax-invariant, unused.

    float* out    = (float*)d_out;
    float* scores = (float*)d_ws;                          // B*T floats
    float* h2     = (float*)d_ws + (size_t)BB * TT;        // B*U floats
    short* W1T    = (short*)(h2 + (size_t)BB * UU);        // U*D bf16

    prep_kernel<<<256 + BB, 256, 0, stream>>>(W1, W1T, last, W2, b1, b2, h2);
    score_kernel<<<BB * (TT / 64), 256, 0, stream>>>(full, W1T, h2, V, scores);
    softmax_kernel<<<BB, 256, 0, stream>>>(scores, out);
    context_kernel<<<256, 256, 0, stream>>>(full, scores, out);
}

// Round 5
// 300.059 us; speedup vs baseline: 1.0495x; 1.0495x over previous
//
#include <hip/hip_runtime.h>
#include <math.h>

// Attention pooling: context[b,d] = sum_t softmax_t( V . tanh(full[b,t,:]@W1 + last[b,:]@W2 + b1+b2) ) * full[b,t,d]
// B=32 T=2048 D=512 U=512, fp32 in/out. bV softmax-invariant -> dropped; b1+b2 folded into h2.
// R5: score kernel m97-faithful: BOTH operands via global_load_lds (A staged fp32, converted at
//     frag-build; B bf16), XOR-swizzled chunk slots (<=2-way LDS conflicts = free), 2-barrier K-loop.
//     Softmax kernel eliminated: context recomputes softmax per block from raw scores; d_out zeroed
//     via hipMemsetAsync.
// ws (floats): scores [B*T] @0 (raw, unnormalized), h2 [B*U] @B*T, then W1T [U*D] bf16 (shorts).

#define BB 32
#define TT 2048
#define DD 512
#define UU 512

typedef short bf16x8 __attribute__((ext_vector_type(8)));
typedef float f32x4  __attribute__((ext_vector_type(4)));

static __device__ __forceinline__ short f2bf(float f) {
    unsigned x = __float_as_uint(f);
    return (short)((x + 0x7fffu + ((x >> 16) & 1u)) >> 16);   // RNE
}

static __device__ __forceinline__ float fast_tanh(float x) {
    float e = __expf(2.f * x);
    return 1.f - 2.f * __builtin_amdgcn_rcpf(e + 1.f);
}

// ---------------- prep: blocks [0,256): W1T[u][d]=bf16(W1[d][u]); [256,288): h2 ----------------
__global__ __launch_bounds__(256) void prep_kernel(const float* __restrict__ W1,
                                                   short* __restrict__ W1T,
                                                   const float* __restrict__ last,
                                                   const float* __restrict__ W2,
                                                   const float* __restrict__ b1,
                                                   const float* __restrict__ b2,
                                                   float* __restrict__ h2) {
    __shared__ float tile[32][33];
    __shared__ float ls[DD];
    const int bid = blockIdx.x;
    const int tid = threadIdx.x;
    if (bid < 256) {
        const int tr = (bid >> 4) << 5;   // d-block origin
        const int tc = (bid & 15) << 5;   // u-block origin
#pragma unroll
        for (int p = 0; p < 4; ++p) {
            const int r = p * 8 + (tid >> 5), c = tid & 31;
            tile[r][c] = W1[(size_t)(tr + r) * UU + tc + c];
        }
        __syncthreads();
#pragma unroll
        for (int p = 0; p < 4; ++p) {
            const int r = p * 8 + (tid >> 5), c = tid & 31;    // r=u-local, c=d-local
            W1T[(size_t)(tc + r) * DD + tr + c] = f2bf(tile[c][r]);
        }
    } else {
        const int b = bid - 256;
        for (int i = tid; i < DD; i += 256) ls[i] = last[b * DD + i];
        __syncthreads();
        float a0 = 0.f, a1 = 0.f;
#pragma unroll 8
        for (int d = 0; d < DD; ++d) {
            const float l = ls[d];
            a0 += l * W2[d * UU + tid];
            a1 += l * W2[d * UU + tid + 256];
        }
        h2[b * UU + tid]       = a0 + b1[tid] + b2[tid];
        h2[b * UU + tid + 256] = a1 + b1[tid + 256] + b2[tid + 256];
    }
}

// ---------------- score: raw scores[b,t] = V . tanh(full[b,t,:]@W1 + h2[b,:]) — bf16 MFMA ----------------
// 1024 blocks: b = bid>>5, t0 = (bid&31)*64. 4 waves; wave w owns u in [w*128,(w+1)*128).
// K-loop BK=32, single-buffer, 2 barriers/step (m97 structure):
//   A: fp32 chunks (16B = 4 floats), slot(r,c) = r*8 + (c ^ (r&7));  8 KB
//   B: bf16 chunks (16B = 8 shorts), slot(u,kc) = u*4 + (kc ^ (u&3) ^ ((u>>2)&3)); 32 KB
// Both DMA'd with global_load_lds(16) (wave-uniform base + lane*16). Frag reads <=2-way conflicted.
__global__ __launch_bounds__(256, 2) void score_kernel(const float* __restrict__ full,
                                                       const short* __restrict__ W1T,
                                                       const float* __restrict__ h2,
                                                       const float* __restrict__ V,
                                                       float* __restrict__ scores) {
    __shared__ __align__(16) float a32[64 * 32];     // 512 chunks, swizzled
    __shared__ __align__(16) short blds[512 * 32];   // 2048 chunks, swizzled
    __shared__ float score_red[4][64];

    const int bid = blockIdx.x;
    const int b  = bid >> 5;
    const int t0 = (bid & 31) << 6;
    const int tid = threadIdx.x;
    const int w    = tid >> 6;
    const int lane = tid & 63;
    const int quad = lane >> 4;
    const int col  = lane & 15;

    f32x4 acc[4][8];
#pragma unroll
    for (int i = 0; i < 4; ++i)
#pragma unroll
        for (int j = 0; j < 8; ++j) acc[i][j] = (f32x4){0.f, 0.f, 0.f, 0.f};

    const size_t fullbase = (size_t)(b * TT + t0) * DD;

    for (int ko = 0; ko < 16; ++ko) {
        if (ko) __syncthreads();          // protect single-buffered LDS
        // A DMA: 512 chunks, 2 per wave-lane
#pragma unroll
        for (int i = 0; i < 2; ++i) {
            const int id = w * 128 + i * 64 + lane;
            const int r  = id >> 3;
            const int cc = (id & 7) ^ (r & 7);
            const float* g = &full[fullbase + (size_t)r * DD + ko * 32 + cc * 4];
            __builtin_amdgcn_global_load_lds(
                (const __attribute__((address_space(1))) void*)g,
                (__attribute__((address_space(3))) void*)&a32[(w * 128 + i * 64) * 4],
                16, 0, 0);
        }
        // B DMA: 2048 chunks, 8 per wave-lane
#pragma unroll
        for (int i = 0; i < 8; ++i) {
            const int id = w * 512 + i * 64 + lane;
            const int u  = id >> 2;
            const int kc = (id & 3) ^ (u & 3) ^ ((u >> 2) & 3);
            const short* g = &W1T[(size_t)u * DD + ko * 32 + kc * 8];
            __builtin_amdgcn_global_load_lds(
                (const __attribute__((address_space(1))) void*)g,
                (__attribute__((address_space(3))) void*)&blds[(w * 512 + i * 64) * 8],
                16, 0, 0);
        }
        __syncthreads();                  // drain DMA

        bf16x8 af[4];
#pragma unroll
        for (int mt = 0; mt < 4; ++mt) {
            const int r = mt * 16 + col;
            const f32x4 lo = *(const f32x4*)&a32[(r * 8 + ((quad * 2 + 0) ^ (r & 7))) * 4];
            const f32x4 hi = *(const f32x4*)&a32[(r * 8 + ((quad * 2 + 1) ^ (r & 7))) * 4];
            af[mt] = (bf16x8){f2bf(lo.x), f2bf(lo.y), f2bf(lo.z), f2bf(lo.w),
                              f2bf(hi.x), f2bf(hi.y), f2bf(hi.z), f2bf(hi.w)};
        }
#pragma unroll
        for (int nt = 0; nt < 8; ++nt) {
            const int u  = w * 128 + nt * 16 + col;
            const int sl = u * 4 + (quad ^ (u & 3) ^ ((u >> 2) & 3));
            const bf16x8 bf = *(const bf16x8*)&blds[sl * 8];
#pragma unroll
            for (int mt = 0; mt < 4; ++mt)
                acc[mt][nt] = __builtin_amdgcn_mfma_f32_16x16x32_bf16(af[mt], bf, acc[mt][nt], 0, 0, 0);
        }
    }

    // epilogue: tanh + dot with V over this wave's u-slice; rows = mt*16 + quad*4 + r
    float srow[16];
#pragma unroll
    for (int i = 0; i < 16; ++i) srow[i] = 0.f;
#pragma unroll
    for (int nt = 0; nt < 8; ++nt) {
        const int u = w * 128 + nt * 16 + col;
        const float hv = h2[b * UU + u];
        const float vv = V[u];
#pragma unroll
        for (int mt = 0; mt < 4; ++mt)
#pragma unroll
            for (int r = 0; r < 4; ++r)
                srow[mt * 4 + r] += fast_tanh(acc[mt][nt][r] + hv) * vv;
    }
#pragma unroll
    for (int off = 1; off < 16; off <<= 1) {
#pragma unroll
        for (int i = 0; i < 16; ++i) srow[i] += __shfl_xor(srow[i], off, 64);
    }
    if (col == 0) {
#pragma unroll
        for (int mt = 0; mt < 4; ++mt)
#pragma unroll
            for (int r = 0; r < 4; ++r)
                score_red[w][mt * 16 + quad * 4 + r] = srow[mt * 4 + r];
    }
    __syncthreads();
    if (tid < 64)
        scores[b * TT + t0 + tid] = score_red[0][tid] + score_red[1][tid] +
                                    score_red[2][tid] + score_red[3][tid];
}

// ---------------- context (softmax fused): block owns (b, 128-d-slice, T-half) ----------------
// 256 blocks: b(5) | dslice(2) | thalf(1). Each block redundantly reduces softmax stats over all
// T=2048 raw scores (8 KB), keeps unnormalized exp weights for its T-half, applies 1/sum at the end.
__global__ __launch_bounds__(256) void context_kernel(const float* __restrict__ full,
                                                      const float* __restrict__ scores,
                                                      float* __restrict__ out) {
    const int bid = blockIdx.x;
    const int b  = bid >> 3;
    const int d0 = ((bid >> 1) & 3) * 128;
    const int t0 = (bid & 1) * 1024;
    const int tid = threadIdx.x;
    const int c  = tid & 31;              // float4 column: d = d0 + c*4
    const int tr = tid >> 5;              // t residue mod 8

    __shared__ float red[256];
    __shared__ float ps[1024];            // unnormalized exp for this T-half
    __shared__ float4 red4[256];

    float local[8];
    float m = -1e30f;
#pragma unroll
    for (int j = 0; j < 8; ++j) {
        local[j] = scores[b * TT + j * 256 + tid];
        m = fmaxf(m, local[j]);
    }
    red[tid] = m;
    __syncthreads();
    for (int s = 128; s > 0; s >>= 1) {
        if (tid < s) red[tid] = fmaxf(red[tid], red[tid + s]);
        __syncthreads();
    }
    const float mx = red[0];
    __syncthreads();

    float sum = 0.f;
    float e[8];
#pragma unroll
    for (int j = 0; j < 8; ++j) {
        e[j] = __expf(local[j] - mx);
        sum += e[j];
    }
    const int jbase = t0 >> 8;            // 0 or 4
#pragma unroll
    for (int i = 0; i < 4; ++i) ps[i * 256 + tid] = e[jbase + i];
    red[tid] = sum;
    __syncthreads();
    for (int s = 128; s > 0; s >>= 1) {
        if (tid < s) red[tid] += red[tid + s];
        __syncthreads();
    }
    const float inv = 1.f / red[0];

    float ax = 0.f, ay = 0.f, az = 0.f, aw = 0.f;
    const float* base = full + ((size_t)(b * TT + t0)) * DD + d0;
#pragma unroll 4
    for (int it = 0; it < 128; ++it) {
        const int t = it * 8 + tr;
        const float4 v = *(const float4*)&base[(size_t)t * DD + c * 4];
        const float wg = ps[t];
        ax += wg * v.x; ay += wg * v.y; az += wg * v.z; aw += wg * v.w;
    }
    red4[tid] = make_float4(ax, ay, az, aw);
    __syncthreads();
    if (tid < 32) {
        float4 s = red4[tid];
#pragma unroll
        for (int g = 1; g < 8; ++g) {
            const float4 o = red4[g * 32 + tid];
            s.x += o.x; s.y += o.y; s.z += o.z; s.w += o.w;
        }
        atomicAdd(&out[b * DD + d0 + tid * 4 + 0], s.x * inv);
        atomicAdd(&out[b * DD + d0 + tid * 4 + 1], s.y * inv);
        atomicAdd(&out[b * DD + d0 + tid * 4 + 2], s.z * inv);
        atomicAdd(&out[b * DD + d0 + tid * 4 + 3], s.w * inv);
    }
}

extern "C" void kernel_launch(void* const* d_in, const int* in_sizes, int n_in,
                              void* d_out, int out_size, void* d_ws, size_t ws_size,
                              hipStream_t stream) {
    const float* full = (const float*)d_in[0];
    const float* last = (const float*)d_in[1];
    const float* W1   = (const float*)d_in[2];
    const float* b1   = (const float*)d_in[3];
    const float* W2   = (const float*)d_in[4];
    const float* b2   = (const float*)d_in[5];
    const float* V    = (const float*)d_in[6];
    // d_in[7] = bV: softmax-invariant, unused.

    float* out    = (float*)d_out;
    float* scores = (float*)d_ws;                          // B*T floats (raw)
    float* h2     = (float*)d_ws + (size_t)BB * TT;        // B*U floats
    short* W1T    = (short*)(h2 + (size_t)BB * UU);        // U*D bf16

    hipMemsetAsync(d_out, 0, (size_t)out_size * sizeof(float), stream);
    prep_kernel<<<256 + BB, 256, 0, stream>>>(W1, W1T, last, W2, b1, b2, h2);
    score_kernel<<<BB * (TT / 64), 256, 0, stream>>>(full, W1T, h2, V, scores);
    context_kernel<<<256, 256, 0, stream>>>(full, scores, out);
}

// Round 6
// 293.191 us; speedup vs baseline: 1.0741x; 1.0234x over previous
//
#include <hip/hip_runtime.h>
#include <math.h>

// Attention pooling: context[b,d] = sum_t softmax_t( V . tanh(full[b,t,:]@W1 + last[b,:]@W2 + b1+b2) ) * full[b,t,d]
// B=32 T=2048 D=512 U=512, fp32 in/out. bV softmax-invariant -> dropped; b1+b2 folded into h2.
// R6: score U-split x2 (N=256/block, 64 AGPR/wave, 25 KB LDS -> ~3 blocks/CU for barrier overlap),
//     partial scores combined via atomicAdd (exact: 2-term fp32 add is commutative).
//     prep: h2 parallelized to 128 blocks; 2 zero-blocks replace both hipMemsetAsync nodes.
//     context: 512 blocks (2/CU), softmax recomputed per block.
// ws (floats): scores [B*T] @0 (zeroed by prep, atomicAdd by score), h2 [B*U] @B*T, then W1T [U*D] bf16.

#define BB 32
#define TT 2048
#define DD 512
#define UU 512

typedef short bf16x8 __attribute__((ext_vector_type(8)));
typedef float f32x4  __attribute__((ext_vector_type(4)));

static __device__ __forceinline__ short f2bf(float f) {
    unsigned x = __float_as_uint(f);
    return (short)((x + 0x7fffu + ((x >> 16) & 1u)) >> 16);   // RNE
}

static __device__ __forceinline__ float fast_tanh(float x) {
    float e = __expf(2.f * x);
    return 1.f - 2.f * __builtin_amdgcn_rcpf(e + 1.f);
}

// ---------------- prep ----------------
// blocks [0,256): W1T[u][d] = bf16(W1[d][u]) tile-transposed
// blocks [256,384): h2 slice — block owns (b, 128-u-slice); threads d-split x2 + LDS combine
// blocks [384,386): zero scores / out
__global__ __launch_bounds__(256) void prep_kernel(const float* __restrict__ W1,
                                                   short* __restrict__ W1T,
                                                   const float* __restrict__ last,
                                                   const float* __restrict__ W2,
                                                   const float* __restrict__ b1,
                                                   const float* __restrict__ b2,
                                                   float* __restrict__ h2,
                                                   float* __restrict__ scores,
                                                   float* __restrict__ out) {
    __shared__ float tile[32][33];
    __shared__ float ls[DD];
    __shared__ float part[256];
    const int bid = blockIdx.x;
    const int tid = threadIdx.x;
    if (bid < 256) {
        const int tr = (bid >> 4) << 5;   // d-block origin
        const int tc = (bid & 15) << 5;   // u-block origin
#pragma unroll
        for (int p = 0; p < 4; ++p) {
            const int r = p * 8 + (tid >> 5), c = tid & 31;
            tile[r][c] = W1[(size_t)(tr + r) * UU + tc + c];
        }
        __syncthreads();
#pragma unroll
        for (int p = 0; p < 4; ++p) {
            const int r = p * 8 + (tid >> 5), c = tid & 31;    // r=u-local, c=d-local
            W1T[(size_t)(tc + r) * DD + tr + c] = f2bf(tile[c][r]);
        }
    } else if (bid < 384) {
        const int b2i = bid - 256;
        const int b  = b2i >> 2;
        const int u0 = (b2i & 3) << 7;
        for (int i = tid; i < DD; i += 256) ls[i] = last[b * DD + i];
        __syncthreads();
        const int uu = tid & 127;
        const int dh = tid >> 7;
        float acc = 0.f;
#pragma unroll 8
        for (int d = dh * 256; d < dh * 256 + 256; ++d)
            acc += ls[d] * W2[d * UU + u0 + uu];
        part[tid] = acc;
        __syncthreads();
        if (tid < 128) {
            const int u = u0 + tid;
            h2[b * UU + u] = part[tid] + part[tid + 128] + b1[u] + b2[u];
        }
    } else if (bid == 384) {
        float4 z = make_float4(0.f, 0.f, 0.f, 0.f);
        for (int i = tid; i < (BB * TT) / 4; i += 256) ((float4*)scores)[i] = z;
    } else {
        float4 z = make_float4(0.f, 0.f, 0.f, 0.f);
        for (int i = tid; i < (BB * DD) / 4; i += 256) ((float4*)out)[i] = z;
    }
}

// ---------------- score: scores[b,t] += V_slice . tanh(full@W1_slice + h2_slice) — bf16 MFMA ----------------
// 2048 blocks: b = bid>>6, t0 = ((bid>>1)&31)*64, u-slice us = bid&1 (256 u each).
// 4 waves; wave w owns u_local in [w*64,(w+1)*64) -> 4 m-frags x 4 n-frags = 64 AGPR.
// K-loop BK=32, both operands via global_load_lds(16), XOR-swizzled chunk slots.
__global__ __launch_bounds__(256, 2) void score_kernel(const float* __restrict__ full,
                                                       const short* __restrict__ W1T,
                                                       const float* __restrict__ h2,
                                                       const float* __restrict__ V,
                                                       float* __restrict__ scores) {
    __shared__ __align__(16) float a32[64 * 32];     // 512 chunks, swizzled, 8 KB
    __shared__ __align__(16) short blds[256 * 32];   // 1024 chunks, swizzled, 16 KB
    __shared__ float score_red[4][64];

    const int bid = blockIdx.x;
    const int b  = bid >> 6;
    const int t0 = ((bid >> 1) & 31) << 6;
    const int u0 = (bid & 1) << 8;
    const int tid = threadIdx.x;
    const int w    = tid >> 6;
    const int lane = tid & 63;
    const int quad = lane >> 4;
    const int col  = lane & 15;

    f32x4 acc[4][4];
#pragma unroll
    for (int i = 0; i < 4; ++i)
#pragma unroll
        for (int j = 0; j < 4; ++j) acc[i][j] = (f32x4){0.f, 0.f, 0.f, 0.f};

    const size_t fullbase = (size_t)(b * TT + t0) * DD;

    for (int ko = 0; ko < 16; ++ko) {
        if (ko) __syncthreads();          // protect single-buffered LDS
        // A DMA: 512 fp32 chunks, 2 per wave-lane; slot(r,cc') = r*8 + (cc' = cc ^ (r&7))
#pragma unroll
        for (int i = 0; i < 2; ++i) {
            const int id = w * 128 + i * 64 + lane;
            const int r  = id >> 3;
            const int cc = (id & 7) ^ (r & 7);
            const float* g = &full[fullbase + (size_t)r * DD + ko * 32 + cc * 4];
            __builtin_amdgcn_global_load_lds(
                (const __attribute__((address_space(1))) void*)g,
                (__attribute__((address_space(3))) void*)&a32[(w * 128 + i * 64) * 4],
                16, 0, 0);
        }
        // B DMA: 1024 bf16 chunks, 4 per wave-lane; slot(u,kc') = u*4 + (kc ^ (u&3) ^ ((u>>2)&3))
#pragma unroll
        for (int i = 0; i < 4; ++i) {
            const int id = w * 256 + i * 64 + lane;
            const int ul = id >> 2;
            const int kc = (id & 3) ^ (ul & 3) ^ ((ul >> 2) & 3);
            const short* g = &W1T[(size_t)(u0 + ul) * DD + ko * 32 + kc * 8];
            __builtin_amdgcn_global_load_lds(
                (const __attribute__((address_space(1))) void*)g,
                (__attribute__((address_space(3))) void*)&blds[(w * 256 + i * 64) * 8],
                16, 0, 0);
        }
        __syncthreads();                  // drain DMA

        bf16x8 af[4];
#pragma unroll
        for (int mt = 0; mt < 4; ++mt) {
            const int r = mt * 16 + col;
            const f32x4 lo = *(const f32x4*)&a32[(r * 8 + ((quad * 2 + 0) ^ (r & 7))) * 4];
            const f32x4 hi = *(const f32x4*)&a32[(r * 8 + ((quad * 2 + 1) ^ (r & 7))) * 4];
            af[mt] = (bf16x8){f2bf(lo.x), f2bf(lo.y), f2bf(lo.z), f2bf(lo.w),
                              f2bf(hi.x), f2bf(hi.y), f2bf(hi.z), f2bf(hi.w)};
        }
#pragma unroll
        for (int nt = 0; nt < 4; ++nt) {
            const int ul = w * 64 + nt * 16 + col;
            const int sl = ul * 4 + (quad ^ (ul & 3) ^ ((ul >> 2) & 3));
            const bf16x8 bf = *(const bf16x8*)&blds[sl * 8];
#pragma unroll
            for (int mt = 0; mt < 4; ++mt)
                acc[mt][nt] = __builtin_amdgcn_mfma_f32_16x16x32_bf16(af[mt], bf, acc[mt][nt], 0, 0, 0);
        }
    }

    // epilogue: tanh + dot with V over this wave's u-slice; rows = mt*16 + quad*4 + r
    float srow[16];
#pragma unroll
    for (int i = 0; i < 16; ++i) srow[i] = 0.f;
#pragma unroll
    for (int nt = 0; nt < 4; ++nt) {
        const int u = u0 + w * 64 + nt * 16 + col;
        const float hv = h2[b * UU + u];
        const float vv = V[u];
#pragma unroll
        for (int mt = 0; mt < 4; ++mt)
#pragma unroll
            for (int r = 0; r < 4; ++r)
                srow[mt * 4 + r] += fast_tanh(acc[mt][nt][r] + hv) * vv;
    }
#pragma unroll
    for (int off = 1; off < 16; off <<= 1) {
#pragma unroll
        for (int i = 0; i < 16; ++i) srow[i] += __shfl_xor(srow[i], off, 64);
    }
    if (col == 0) {
#pragma unroll
        for (int mt = 0; mt < 4; ++mt)
#pragma unroll
            for (int r = 0; r < 4; ++r)
                score_red[w][mt * 16 + quad * 4 + r] = srow[mt * 4 + r];
    }
    __syncthreads();
    if (tid < 64)
        atomicAdd(&scores[b * TT + t0 + tid],
                  score_red[0][tid] + score_red[1][tid] + score_red[2][tid] + score_red[3][tid]);
}

// ---------------- context (softmax fused): block owns (b, 128-d-slice, 512-t-quarter) ----------------
// 512 blocks: b(5) | dslice(2) | tquarter(2). Each block redundantly reduces softmax stats over all
// T=2048 raw scores, keeps unnormalized exp weights for its quarter, applies 1/sum at the end.
__global__ __launch_bounds__(256) void context_kernel(const float* __restrict__ full,
                                                      const float* __restrict__ scores,
                                                      float* __restrict__ out) {
    const int bid = blockIdx.x;
    const int b  = bid >> 4;
    const int d0 = ((bid >> 2) & 3) << 7;
    const int t0 = (bid & 3) << 9;
    const int tid = threadIdx.x;
    const int c  = tid & 31;              // float4 column: d = d0 + c*4
    const int tr = tid >> 5;              // t residue mod 8

    __shared__ float red[256];
    __shared__ float ps[512];             // unnormalized exp for this T-quarter
    __shared__ float4 red4[256];

    float local[8];
    float m = -1e30f;
#pragma unroll
    for (int j = 0; j < 8; ++j) {
        local[j] = scores[b * TT + j * 256 + tid];
        m = fmaxf(m, local[j]);
    }
    red[tid] = m;
    __syncthreads();
    for (int s = 128; s > 0; s >>= 1) {
        if (tid < s) red[tid] = fmaxf(red[tid], red[tid + s]);
        __syncthreads();
    }
    const float mx = red[0];
    __syncthreads();

    float sum = 0.f;
    float e[8];
#pragma unroll
    for (int j = 0; j < 8; ++j) {
        e[j] = __expf(local[j] - mx);
        sum += e[j];
    }
    const int jb = (bid & 3) * 2;
#pragma unroll
    for (int i = 0; i < 2; ++i) ps[i * 256 + tid] = e[jb + i];
    red[tid] = sum;
    __syncthreads();
    for (int s = 128; s > 0; s >>= 1) {
        if (tid < s) red[tid] += red[tid + s];
        __syncthreads();
    }
    const float inv = 1.f / red[0];

    float ax = 0.f, ay = 0.f, az = 0.f, aw = 0.f;
    const float* base = full + ((size_t)(b * TT + t0)) * DD + d0;
#pragma unroll 4
    for (int it = 0; it < 64; ++it) {
        const int t = it * 8 + tr;
        const float4 v = *(const float4*)&base[(size_t)t * DD + c * 4];
        const float wg = ps[t];
        ax += wg * v.x; ay += wg * v.y; az += wg * v.z; aw += wg * v.w;
    }
    red4[tid] = make_float4(ax, ay, az, aw);
    __syncthreads();
    if (tid < 32) {
        float4 s = red4[tid];
#pragma unroll
        for (int g = 1; g < 8; ++g) {
            const float4 o = red4[g * 32 + tid];
            s.x += o.x; s.y += o.y; s.z += o.z; s.w += o.w;
        }
        atomicAdd(&out[b * DD + d0 + tid * 4 + 0], s.x * inv);
        atomicAdd(&out[b * DD + d0 + tid * 4 + 1], s.y * inv);
        atomicAdd(&out[b * DD + d0 + tid * 4 + 2], s.z * inv);
        atomicAdd(&out[b * DD + d0 + tid * 4 + 3], s.w * inv);
    }
}

extern "C" void kernel_launch(void* const* d_in, const int* in_sizes, int n_in,
                              void* d_out, int out_size, void* d_ws, size_t ws_size,
                              hipStream_t stream) {
    const float* full = (const float*)d_in[0];
    const float* last = (const float*)d_in[1];
    const float* W1   = (const float*)d_in[2];
    const float* b1   = (const float*)d_in[3];
    const float* W2   = (const float*)d_in[4];
    const float* b2   = (const float*)d_in[5];
    const float* V    = (const float*)d_in[6];
    // d_in[7] = bV: softmax-invariant, unused.

    float* out    = (float*)d_out;
    float* scores = (float*)d_ws;                          // B*T floats (raw, atomicAdd target)
    float* h2     = (float*)d_ws + (size_t)BB * TT;        // B*U floats
    short* W1T    = (short*)(h2 + (size_t)BB * UU);        // U*D bf16

    prep_kernel<<<386, 256, 0, stream>>>(W1, W1T, last, W2, b1, b2, h2, scores, out);
    score_kernel<<<BB * (TT / 64) * 2, 256, 0, stream>>>(full, W1T, h2, V, scores);
    context_kernel<<<512, 256, 0, stream>>>(full, scores, out);
}

// Round 7
// 270.010 us; speedup vs baseline: 1.1663x; 1.0859x over previous
//
#include <hip/hip_runtime.h>
#include <math.h>

// Attention pooling: context[b,d] = sum_t softmax_t( V . tanh(full[b,t,:]@W1 + last[b,:]@W2 + b1+b2) ) * full[b,t,d]
// B=32 T=2048 D=512 U=512, fp32 in/out. bV softmax-invariant -> dropped; b1+b2 folded into h2.
// R7: flash-style fusion. score kernel (M=128,N=512,BK=64, 512 thr) computes raw scores AND
//     per-tile partial context with local softmax stats (m,l,unnormalized sum) using its L2-hot
//     A tile — the 128 MB context re-read of `full` is eliminated. combine kernel rescales and
//     reduces the 16 partials per batch. No atomics anywhere; out fully overwritten.
// ws (floats): h2 [B*U] @0, m_arr [512] @16384, l_arr [512] @16896, ctx [B*16*D] @17408,
//              W1T [U*D] bf16 @ float-offset 279552. Total ~1.64 MB.

#define BB 32
#define TT 2048
#define DD 512
#define UU 512

typedef short bf16x8 __attribute__((ext_vector_type(8)));
typedef float f32x4  __attribute__((ext_vector_type(4)));

static __device__ __forceinline__ short f2bf(float f) {
    unsigned x = __float_as_uint(f);
    return (short)((x + 0x7fffu + ((x >> 16) & 1u)) >> 16);   // RNE
}

static __device__ __forceinline__ float fast_tanh(float x) {
    float e = __expf(2.f * x);
    return 1.f - 2.f * __builtin_amdgcn_rcpf(e + 1.f);
}

// ---------------- prep ----------------
// blocks [0,256): W1T[u][d] = bf16(W1[d][u]) tile-transposed
// blocks [256,384): h2 slice — block owns (b, 128-u-slice); threads d-split x2 + LDS combine
__global__ __launch_bounds__(256) void prep_kernel(const float* __restrict__ W1,
                                                   short* __restrict__ W1T,
                                                   const float* __restrict__ last,
                                                   const float* __restrict__ W2,
                                                   const float* __restrict__ b1,
                                                   const float* __restrict__ b2,
                                                   float* __restrict__ h2) {
    __shared__ float tile[32][33];
    __shared__ float ls[DD];
    __shared__ float part[256];
    const int bid = blockIdx.x;
    const int tid = threadIdx.x;
    if (bid < 256) {
        const int tr = (bid >> 4) << 5;   // d-block origin
        const int tc = (bid & 15) << 5;   // u-block origin
#pragma unroll
        for (int p = 0; p < 4; ++p) {
            const int r = p * 8 + (tid >> 5), c = tid & 31;
            tile[r][c] = W1[(size_t)(tr + r) * UU + tc + c];
        }
        __syncthreads();
#pragma unroll
        for (int p = 0; p < 4; ++p) {
            const int r = p * 8 + (tid >> 5), c = tid & 31;    // r=u-local, c=d-local
            W1T[(size_t)(tc + r) * DD + tr + c] = f2bf(tile[c][r]);
        }
    } else {
        const int b2i = bid - 256;
        const int b  = b2i >> 2;
        const int u0 = (b2i & 3) << 7;
        for (int i = tid; i < DD; i += 256) ls[i] = last[b * DD + i];
        __syncthreads();
        const int uu = tid & 127;
        const int dh = tid >> 7;
        float acc = 0.f;
#pragma unroll 8
        for (int d = dh * 256; d < dh * 256 + 256; ++d)
            acc += ls[d] * W2[d * UU + u0 + uu];
        part[tid] = acc;
        __syncthreads();
        if (tid < 128) {
            const int u = u0 + tid;
            h2[b * UU + u] = part[tid] + part[tid + 128] + b1[u] + b2[u];
        }
    }
}

// ---------------- score + partial context (flash-style) ----------------
// 512 blocks: b = bid>>4, tile = bid&15, t0 = tile*128. 512 threads = 8 waves, 2(M) x 4(N) grid;
// wave tile 64x128 (4 m-frags x 8 n-frags, acc=128). K-loop BK=64 (8 steps, 2 barriers each).
// LDS chunk slots XOR-swizzled: A slot(r,cc)=r*16+(cc^(r&15)) fp32x4; B slot(u,kc)=u*8+(kc^(u&7)) bf16x8.
// Epilogue: tanh+V dot -> 128 raw scores -> block max m, e_t, l -> partial ctx[d]=sum_t e_t*full[t,d]
// from the L2-hot tile. Writes ctx[bid][512], m_arr[bid], l_arr[bid].
__global__ __launch_bounds__(512) void score_kernel(const float* __restrict__ full,
                                                    const short* __restrict__ W1T,
                                                    const float* __restrict__ h2,
                                                    const float* __restrict__ V,
                                                    float* __restrict__ ctx,
                                                    float* __restrict__ m_arr,
                                                    float* __restrict__ l_arr) {
    __shared__ __align__(16) float a32[128 * 64];    // 2048 chunks, 32 KB
    __shared__ __align__(16) short blds[512 * 64];   // 4096 chunks, 64 KB
    __shared__ float red64[8][64];
    __shared__ float esc[128];
    __shared__ float sred[8];
    __shared__ __align__(16) float red4[4][128][4];  // 8 KB

    const int bid = blockIdx.x;
    const int b    = bid >> 4;
    const int t0   = (bid & 15) << 7;
    const int tid  = threadIdx.x;
    const int w    = tid >> 6;
    const int lane = tid & 63;
    const int quad = lane >> 4;
    const int col  = lane & 15;
    const int wm   = w >> 2;
    const int wn   = w & 3;

    f32x4 acc[4][8];
#pragma unroll
    for (int i = 0; i < 4; ++i)
#pragma unroll
        for (int j = 0; j < 8; ++j) acc[i][j] = (f32x4){0.f, 0.f, 0.f, 0.f};

    const size_t fullbase = (size_t)(b * TT + t0) * DD;

    for (int ko = 0; ko < 8; ++ko) {
        if (ko) __syncthreads();
        // A DMA: 2048 fp32x4 chunks, 4 issues/wave
#pragma unroll
        for (int i = 0; i < 4; ++i) {
            const int sb = w * 256 + i * 64;
            const int s  = sb + lane;
            const int r  = s >> 4;
            const int cc = (s & 15) ^ (r & 15);
            const float* g = &full[fullbase + (size_t)r * DD + ko * 64 + cc * 4];
            __builtin_amdgcn_global_load_lds(
                (const __attribute__((address_space(1))) void*)g,
                (__attribute__((address_space(3))) void*)&a32[sb * 4], 16, 0, 0);
        }
        // B DMA: 4096 bf16x8 chunks, 8 issues/wave
#pragma unroll
        for (int i = 0; i < 8; ++i) {
            const int sb = w * 512 + i * 64;
            const int s  = sb + lane;
            const int u  = s >> 3;
            const int kc = (s & 7) ^ (u & 7);
            const short* g = &W1T[(size_t)u * DD + ko * 64 + kc * 8];
            __builtin_amdgcn_global_load_lds(
                (const __attribute__((address_space(1))) void*)g,
                (__attribute__((address_space(3))) void*)&blds[sb * 8], 16, 0, 0);
        }
        __syncthreads();

#pragma unroll
        for (int ki = 0; ki < 2; ++ki) {
            bf16x8 af[4];
#pragma unroll
            for (int mt = 0; mt < 4; ++mt) {
                const int r   = wm * 64 + mt * 16 + col;
                const int cc0 = ki * 8 + quad * 2;
                const f32x4 lo = *(const f32x4*)&a32[(r * 16 + (cc0 ^ (r & 15))) * 4];
                const f32x4 hi = *(const f32x4*)&a32[(r * 16 + ((cc0 + 1) ^ (r & 15))) * 4];
                af[mt] = (bf16x8){f2bf(lo.x), f2bf(lo.y), f2bf(lo.z), f2bf(lo.w),
                                  f2bf(hi.x), f2bf(hi.y), f2bf(hi.z), f2bf(hi.w)};
            }
#pragma unroll
            for (int nt = 0; nt < 8; ++nt) {
                const int u  = wn * 128 + nt * 16 + col;
                const int kc = ki * 4 + quad;
                const bf16x8 bf = *(const bf16x8*)&blds[(u * 8 + (kc ^ (u & 7))) * 8];
#pragma unroll
                for (int mt = 0; mt < 4; ++mt)
                    acc[mt][nt] = __builtin_amdgcn_mfma_f32_16x16x32_bf16(af[mt], bf, acc[mt][nt], 0, 0, 0);
            }
        }
    }

    // ---- raw scores: tanh + V-dot, reduce over this wave's 128 u, then over wn ----
    float srow[16];
#pragma unroll
    for (int i = 0; i < 16; ++i) srow[i] = 0.f;
#pragma unroll
    for (int nt = 0; nt < 8; ++nt) {
        const int u = wn * 128 + nt * 16 + col;
        const float hv = h2[b * UU + u];
        const float vv = V[u];
#pragma unroll
        for (int mt = 0; mt < 4; ++mt)
#pragma unroll
            for (int r = 0; r < 4; ++r)
                srow[mt * 4 + r] += fast_tanh(acc[mt][nt][r] + hv) * vv;
    }
#pragma unroll
    for (int off = 1; off < 16; off <<= 1) {
#pragma unroll
        for (int i = 0; i < 16; ++i) srow[i] += __shfl_xor(srow[i], off, 64);
    }
    if (col == 0) {
#pragma unroll
        for (int mt = 0; mt < 4; ++mt)
#pragma unroll
            for (int r = 0; r < 4; ++r)
                red64[w][mt * 16 + quad * 4 + r] = srow[mt * 4 + r];
    }
    __syncthreads();

    // ---- softmax stats over the 128 rows (threads 0..127 hold row tid) ----
    float sv = 0.f;
    if (tid < 128) {
        const int wmX = tid >> 6, rr = tid & 63;
        sv = red64[wmX * 4 + 0][rr] + red64[wmX * 4 + 1][rr] +
             red64[wmX * 4 + 2][rr] + red64[wmX * 4 + 3][rr];
        float mv = sv;
#pragma unroll
        for (int off = 1; off < 64; off <<= 1) mv = fmaxf(mv, __shfl_xor(mv, off, 64));
        if (lane == 0) sred[w] = mv;
    }
    __syncthreads();
    const float M = fmaxf(sred[0], sred[1]);
    if (tid < 128) {
        float e = __expf(sv - M);
        esc[tid] = e;
#pragma unroll
        for (int off = 1; off < 64; off <<= 1) e += __shfl_xor(e, off, 64);
        if (lane == 0) sred[4 + w] = e;
    }
    __syncthreads();
    if (tid == 0) { m_arr[bid] = M; l_arr[bid] = sred[4] + sred[5]; }

    // ---- partial context from the (L2-hot) tile: ctx[d] = sum_t esc[t] * full[t,d] ----
    const int c  = tid & 127;             // float4 column, d = c*4
    const int tp = tid >> 7;              // t residue mod 4
    float ax = 0.f, ay = 0.f, az = 0.f, aw = 0.f;
#pragma unroll 4
    for (int i = 0; i < 32; ++i) {
        const int t = i * 4 + tp;
        const float4 v = *(const float4*)&full[fullbase + (size_t)t * DD + c * 4];
        const float e = esc[t];
        ax += e * v.x; ay += e * v.y; az += e * v.z; aw += e * v.w;
    }
    *(float4*)&red4[tp][c][0] = make_float4(ax, ay, az, aw);
    __syncthreads();
    if (tp == 0) {
        const float4 p0 = *(const float4*)&red4[0][c][0];
        const float4 p1 = *(const float4*)&red4[1][c][0];
        const float4 p2 = *(const float4*)&red4[2][c][0];
        const float4 p3 = *(const float4*)&red4[3][c][0];
        float4 s = make_float4(p0.x + p1.x + p2.x + p3.x,
                               p0.y + p1.y + p2.y + p3.y,
                               p0.z + p1.z + p2.z + p3.z,
                               p0.w + p1.w + p2.w + p3.w);
        *(float4*)&ctx[(size_t)bid * DD + c * 4] = s;
    }
}

// ---------------- combine: out[b,d] = sum_i w_i*ctx[b,i,d] / sum_i w_i*l_i, w_i = e^{m_i - M} ----------------
__global__ __launch_bounds__(256) void combine_kernel(const float* __restrict__ ctx,
                                                      const float* __restrict__ m_arr,
                                                      const float* __restrict__ l_arr,
                                                      float* __restrict__ out) {
    const int b = blockIdx.x;
    const int tid = threadIdx.x;
    __shared__ float wgt[16];
    __shared__ float linv;
    if (tid == 0) {
        float M = -1e30f;
#pragma unroll
        for (int i = 0; i < 16; ++i) M = fmaxf(M, m_arr[b * 16 + i]);
        float l = 0.f;
#pragma unroll
        for (int i = 0; i < 16; ++i) {
            wgt[i] = __expf(m_arr[b * 16 + i] - M);
            l += wgt[i] * l_arr[b * 16 + i];
        }
        linv = 1.f / l;
    }
    __syncthreads();
    float s0 = 0.f, s1 = 0.f;
#pragma unroll
    for (int i = 0; i < 16; ++i) {
        const float wi = wgt[i];
        const float* cp = &ctx[(size_t)(b * 16 + i) * DD + tid * 2];
        s0 += wi * cp[0];
        s1 += wi * cp[1];
    }
    out[b * DD + tid * 2]     = s0 * linv;
    out[b * DD + tid * 2 + 1] = s1 * linv;
}

extern "C" void kernel_launch(void* const* d_in, const int* in_sizes, int n_in,
                              void* d_out, int out_size, void* d_ws, size_t ws_size,
                              hipStream_t stream) {
    const float* full = (const float*)d_in[0];
    const float* last = (const float*)d_in[1];
    const float* W1   = (const float*)d_in[2];
    const float* b1   = (const float*)d_in[3];
    const float* W2   = (const float*)d_in[4];
    const float* b2   = (const float*)d_in[5];
    const float* V    = (const float*)d_in[6];
    // d_in[7] = bV: softmax-invariant, unused.

    float* out   = (float*)d_out;
    float* h2    = (float*)d_ws;                    // 16384 floats
    float* m_arr = h2 + (size_t)BB * UU;            // 512
    float* l_arr = m_arr + 512;                     // 512
    float* ctx   = l_arr + 512;                     // 32*16*512 = 262144
    short* W1T   = (short*)(ctx + (size_t)BB * 16 * DD);  // U*D bf16

    prep_kernel<<<384, 256, 0, stream>>>(W1, W1T, last, W2, b1, b2, h2);
    score_kernel<<<BB * 16, 512, 0, stream>>>(full, W1T, h2, V, ctx, m_arr, l_arr);
    combine_kernel<<<BB, 256, 0, stream>>>(ctx, m_arr, l_arr, out);
}